// Round 13
// baseline (653.788 us; speedup 1.0000x reference)
//
#include <hip/hip_runtime.h>
#include <cstdint>

#define EPSV 1e-5f
typedef unsigned short u16;
typedef __attribute__((ext_vector_type(8))) short bh8;   // 8 bf16 (4 VGPRs)
typedef __attribute__((ext_vector_type(4))) float f4;

__device__ __forceinline__ float bf2f(u16 h) { return __uint_as_float((unsigned)h << 16); }
__device__ __forceinline__ u16 f2bf(float x) {
    unsigned u = __float_as_uint(x);
    u += 0x7fffu + ((u >> 16) & 1u);          // RNE
    return (u16)(u >> 16);
}

// async global->LDS, 16B per lane; LDS dest = wave-uniform base + lane*16
__device__ __forceinline__ void gl16(const void* g, const void* s) {
    __builtin_amdgcn_global_load_lds(
        reinterpret_cast<const __attribute__((address_space(1))) void*>((uintptr_t)g),
        reinterpret_cast<__attribute__((address_space(3))) void*>((unsigned)(uintptr_t)s),
        16, 0, 0);
}

// ---------------------------------------------------------------------------
// 128x128 2-phase dbuf NT hi/lo core (4 waves, 64 KB LDS) — round-6 proven.
// Chunk-XOR swizzle both sides. Used by gemm_u / gemm_term_p.
// ---------------------------------------------------------------------------
__device__ __forceinline__ void core2(
    const u16* __restrict__ Ah, const u16* __restrict__ Al,
    const u16* __restrict__ Bh, const u16* __restrict__ Bl,
    long ldA, long ldB, int K, int rowA0, int rowB0,
    u16* lds, f4 acc[4][4])
{
    const int tid = threadIdx.x, l = tid & 63, w = tid >> 6;
    const int wr = w >> 1, wc = w & 1;
    const int srow = tid >> 2;
    const int schunk = ((tid & 3) ^ ((tid >> 3) & 3)) << 3;     // elems
    const size_t aoff = (size_t)(rowA0 + srow) * ldA + schunk;
    const size_t boff = (size_t)(rowB0 + srow) * ldB + schunk;
    const size_t a64 = (size_t)64 * ldA, b64 = (size_t)64 * ldB;
    const int rr = l & 15, cq = l >> 4;
    const int roff = rr * 64 + (((cq ^ ((rr >> 1) & 3))) << 4); // bytes
    char* const base0 = (char*)lds;
    char* const base1 = (char*)lds + 32768;
    const int nt = K >> 5;

#define STAGE_SWZ(base, s0) do { \
    gl16(Ah + aoff + (s0),       (base) +         w * 1024); \
    gl16(Ah + aoff + a64 + (s0), (base) +  4096 + w * 1024); \
    gl16(Al + aoff + (s0),       (base) +  8192 + w * 1024); \
    gl16(Al + aoff + a64 + (s0), (base) + 12288 + w * 1024); \
    gl16(Bh + boff + (s0),       (base) + 16384 + w * 1024); \
    gl16(Bh + boff + b64 + (s0), (base) + 20480 + w * 1024); \
    gl16(Bl + boff + (s0),       (base) + 24576 + w * 1024); \
    gl16(Bl + boff + b64 + (s0), (base) + 28672 + w * 1024); \
} while (0)

    STAGE_SWZ(base0, 0);
    __syncthreads();
    int p = 0;
    for (int t = 0; t < nt; ++t) {
        if (t + 1 < nt) STAGE_SWZ(p ? base0 : base1, (size_t)(t + 1) << 5);
        const char* buf = p ? base1 : base0;
        bh8 a_h[4], a_l[4], b_h[4], b_l[4];
#pragma unroll
        for (int i = 0; i < 4; ++i) {
            a_h[i] = *(const bh8*)(buf + (wr * 4 + i) * 1024 + roff);
            a_l[i] = *(const bh8*)(buf + 8192 + (wr * 4 + i) * 1024 + roff);
            b_h[i] = *(const bh8*)(buf + 16384 + (wc * 4 + i) * 1024 + roff);
            b_l[i] = *(const bh8*)(buf + 24576 + (wc * 4 + i) * 1024 + roff);
        }
#pragma unroll
        for (int i = 0; i < 4; ++i)
#pragma unroll
            for (int j = 0; j < 4; ++j)
                acc[i][j] = __builtin_amdgcn_mfma_f32_16x16x32_bf16(a_h[i], b_h[j], acc[i][j], 0, 0, 0);
#pragma unroll
        for (int i = 0; i < 4; ++i)
#pragma unroll
            for (int j = 0; j < 4; ++j)
                acc[i][j] = __builtin_amdgcn_mfma_f32_16x16x32_bf16(a_h[i], b_l[j], acc[i][j], 0, 0, 0);
#pragma unroll
        for (int i = 0; i < 4; ++i)
#pragma unroll
            for (int j = 0; j < 4; ++j)
                acc[i][j] = __builtin_amdgcn_mfma_f32_16x16x32_bf16(a_l[i], b_h[j], acc[i][j], 0, 0, 0);
        __syncthreads();
        p ^= 1;
    }
#undef STAGE_SWZ
}

// ---------------------------------------------------------------------------
// Stage-1 v9: 512 thr (8 waves 4x2), BM=256 x BN=128, BK=32, 3x48KB ring,
// TWO barriers per K-tile:
//   { ST(t+2) -> counted vmcnt (own slice landed) -> s_barrier [data ready]
//     -> setprio(1) 16 ds_read + 48 MFMA setprio(0)
//     -> lgkmcnt(0) -> s_barrier [release] }
// Cross-wave visibility: every wave confirms its own tile-t loads (vmcnt)
// BEFORE the data-ready barrier; reads happen after it.  Buffer overwrite:
// ST(t+2) targets buf (t-1)%3 whose reads finished before the end-of-(t-1)
// release barrier.  vmcnt counted: t+1,t+2 stay in flight (never 0 mid-loop).
// Fused gx row-mean (wi==0).  full=false (gx): 4 loads/tile, skip lh pass.
// ---------------------------------------------------------------------------
__global__ __launch_bounds__(512) void gemm_s1_v9(
    const u16* __restrict__ Xh, const u16* __restrict__ Xl,
    const u16* __restrict__ W0h, const u16* __restrict__ W0l,
    const u16* __restrict__ W1h, const u16* __restrict__ W1l,
    const u16* __restrict__ W2h, const u16* __restrict__ W2l,
    const float* __restrict__ bn0, const float* __restrict__ bn1,
    const float* __restrict__ bn2,
    float* __restrict__ gxc_part,
    u16* __restrict__ Y1h, u16* __restrict__ Y1l,
    u16* __restrict__ Y2h, u16* __restrict__ Y2l)
{
    const int h = blockIdx.x;
    const int orig = (h & 7) * 120 + (h >> 3);
    const int ow = orig % 15;
    const int rest = orig / 15;               // 0..63
    const int ct = rest & 1, bz = rest >> 1;
    const int wi = ow / 5, otw = ow % 5;
    const bool full = (wi != 0);

    const u16* Bh = wi == 0 ? W0h : wi == 1 ? W1h : W2h;
    const u16* Bl = wi == 0 ? W0l : wi == 1 ? W1l : W2l;
    const float* bnp = wi == 0 ? bn0 : wi == 1 ? bn1 : bn2;
    u16* Yh = wi == 1 ? Y1h : Y2h;
    u16* Yl = wi == 1 ? Y1l : Y2l;

    __shared__ u16 lds[73728];                // 144 KB = 3 x 48 KB ring

    const int tid = threadIdx.x, l = tid & 63, w = tid >> 6;
    const int wm = w >> 1, wn = w & 1;        // 4(M) x 2(N) wave grid
    const long ldK = 2304;
    const int rowA0 = bz * 512 + ct * 256;
    const int rowB0 = otw * 128;
    const int srow = tid >> 2;                // 0..127
    const int schunk = ((tid & 3) ^ ((tid >> 3) & 3)) << 3;
    const size_t aoff = (size_t)(rowA0 + srow) * ldK + schunk;
    const size_t boff = (size_t)(rowB0 + srow) * ldK + schunk;
    const size_t a128 = (size_t)128 * ldK;
    const int rr = l & 15, cq2 = l >> 4;
    const int roff = rr * 64 + ((cq2 ^ ((rr >> 1) & 3)) << 4);
    char* const ldsb = (char*)lds;
    const int nt = 72;                        // 2304/32

#define ST_ALL(sb, s0) do { \
    gl16(Xh + aoff + (s0),        (sb) +         w * 1024); \
    gl16(Xh + aoff + a128 + (s0), (sb) +  8192 + w * 1024); \
    if (full) { \
        gl16(Xl + aoff + (s0),        (sb) + 16384 + w * 1024); \
        gl16(Xl + aoff + a128 + (s0), (sb) + 24576 + w * 1024); \
    } \
    gl16(Bh + boff + (s0), (sb) + 32768 + w * 1024); \
    gl16(Bl + boff + (s0), (sb) + 40960 + w * 1024); \
} while (0)

    f4 acc[4][4];
    const f4 z4 = {0.f, 0.f, 0.f, 0.f};
#pragma unroll
    for (int i = 0; i < 4; ++i)
#pragma unroll
        for (int j = 0; j < 4; ++j) acc[i][j] = z4;

    // prologue: stage tiles 0 and 1 (no wait; loop's counted vmcnt covers it)
    ST_ALL(ldsb, 0);
    ST_ALL(ldsb + 49152, 32);

    for (int t = 0; t < nt; ++t) {
        const char* buf = ldsb + (t % 3) * 49152;
        char* sbuf = ldsb + ((t + 2) % 3) * 49152;
        const bool pre = (t + 2 < nt);

        if (pre) ST_ALL(sbuf, (t + 2) << 5);
        // counted wait: my slice of tile t landed (t+1,t+2 stay in flight)
        if (pre) {
            if (full) asm volatile("s_waitcnt vmcnt(12)" ::: "memory");
            else      asm volatile("s_waitcnt vmcnt(8)"  ::: "memory");
        } else if (t + 1 < nt) {
            if (full) asm volatile("s_waitcnt vmcnt(6)" ::: "memory");
            else      asm volatile("s_waitcnt vmcnt(4)" ::: "memory");
        } else {
            asm volatile("s_waitcnt vmcnt(0)" ::: "memory");
        }
        __builtin_amdgcn_sched_barrier(0);
        __builtin_amdgcn_s_barrier();         // data-ready: all slices visible

        __builtin_amdgcn_s_setprio(1);
        bh8 a_h[4], b_h[4], a_l[4], b_l[4];
#pragma unroll
        for (int i = 0; i < 4; ++i)
            a_h[i] = *(const bh8*)(buf + (wm * 4 + i) * 1024 + roff);
#pragma unroll
        for (int j = 0; j < 4; ++j) {
            b_h[j] = *(const bh8*)(buf + 32768 + (wn * 4 + j) * 1024 + roff);
            b_l[j] = *(const bh8*)(buf + 40960 + (wn * 4 + j) * 1024 + roff);
        }
        if (full) {
#pragma unroll
            for (int i = 0; i < 4; ++i)
                a_l[i] = *(const bh8*)(buf + 16384 + (wm * 4 + i) * 1024 + roff);
        }
#pragma unroll
        for (int i = 0; i < 4; ++i)
#pragma unroll
            for (int j = 0; j < 4; ++j)
                acc[i][j] = __builtin_amdgcn_mfma_f32_16x16x32_bf16(a_h[i], b_h[j], acc[i][j], 0, 0, 0);
#pragma unroll
        for (int i = 0; i < 4; ++i)
#pragma unroll
            for (int j = 0; j < 4; ++j)
                acc[i][j] = __builtin_amdgcn_mfma_f32_16x16x32_bf16(a_h[i], b_l[j], acc[i][j], 0, 0, 0);
        if (full) {
#pragma unroll
            for (int i = 0; i < 4; ++i)
#pragma unroll
                for (int j = 0; j < 4; ++j)
                    acc[i][j] = __builtin_amdgcn_mfma_f32_16x16x32_bf16(a_l[i], b_h[j], acc[i][j], 0, 0, 0);
        }
        __builtin_amdgcn_s_setprio(0);

        asm volatile("s_waitcnt lgkmcnt(0)" ::: "memory");
        __builtin_amdgcn_sched_barrier(0);
        __builtin_amdgcn_s_barrier();         // release: buffer t%3 reusable
    }
#undef ST_ALL

    const int mb = ct * 256 + wm * 64;        // c within batch
    const int nbw = otw * 128 + wn * 64;      // o
    const int lm = l & 15, cq = l >> 4;

    if (wi == 0) {
        // fused row-mean partial: sum y over this block's o-range per c row
        float rs[4][4] = {};
#pragma unroll
        for (int j = 0; j < 4; ++j) {
            const int o = nbw + j * 16 + lm;
            const bool val = (o < 576);
            float sc = 0.f, sh = 0.f;
            if (val) {
                const float gg = bnp[o], be = bnp[576 + o], mm = bnp[1152 + o], vv = bnp[1728 + o];
                sc = gg * rsqrtf(vv + EPSV);
                sh = be - mm * sc;
            }
#pragma unroll
            for (int i = 0; i < 4; ++i)
#pragma unroll
                for (int r = 0; r < 4; ++r)
                    rs[i][r] += val ? fmaxf(acc[i][j][r] * sc + sh, 0.f) : 0.f;
        }
        __syncthreads();                      // safe reuse of lds
        float* ldsF = (float*)lds;
#pragma unroll
        for (int i = 0; i < 4; ++i)
#pragma unroll
            for (int r = 0; r < 4; ++r) {
                float v = rs[i][r];
                v += __shfl_xor(v, 1, 64);
                v += __shfl_xor(v, 2, 64);
                v += __shfl_xor(v, 4, 64);
                v += __shfl_xor(v, 8, 64);
                if (lm == 0)
                    ldsF[wn * 256 + wm * 64 + i * 16 + cq * 4 + r] = v;
            }
        __syncthreads();
        if (tid < 256)
            gxc_part[(size_t)otw * 16384 + (size_t)bz * 512 + ct * 256 + tid]
                = ldsF[tid] + ldsF[256 + tid];
    } else {
        // epilogue: bn + relu, hi/lo split, write Y^T [b*512+c][640]
#pragma unroll
        for (int j = 0; j < 4; ++j) {
            const int o = nbw + j * 16 + lm;
            const bool val = (o < 576);
            float sc = 0.f, sh = 0.f;
            if (val) {
                const float gg = bnp[o], be = bnp[576 + o], mm = bnp[1152 + o], vv = bnp[1728 + o];
                sc = gg * rsqrtf(vv + EPSV);
                sh = be - mm * sc;
            }
#pragma unroll
            for (int i = 0; i < 4; ++i) {
                const int c = mb + i * 16 + (cq << 2);
#pragma unroll
                for (int r = 0; r < 4; ++r) {
                    const float y = val ? fmaxf(acc[i][j][r] * sc + sh, 0.f) : 0.f;
                    const u16 hh = f2bf(y);
                    const u16 lo = f2bf(y - bf2f(hh));
                    const size_t off = ((size_t)bz * 512 + c + r) * 640 + o;
                    Yh[off] = hh; Yl[off] = lo;
                }
            }
        }
    }
}

// ---------------------------------------------------------------------------
// U GEMMs: U1[i][o] = sum_j Wgg[i][j]    * phi_nt[o][j]
//          U2[i][o] = sum_j Wgg[i][512+j]* theta_nt[o][j]
// written as hi/lo planes [32][128][640]. 320 blocks = 8*40 swizzle.
// ---------------------------------------------------------------------------
__global__ __launch_bounds__(256) void gemm_u(
    const u16* __restrict__ Wggh, const u16* __restrict__ Wggl,
    const u16* __restrict__ tnth, const u16* __restrict__ tntl,
    const u16* __restrict__ pnth, const u16* __restrict__ pntl,
    u16* __restrict__ U1h, u16* __restrict__ U1l,
    u16* __restrict__ U2h, u16* __restrict__ U2l)
{
    const int h = blockIdx.x;
    const int orig = (h & 7) * 40 + (h >> 3);
    const int ot = orig % 5;
    const int rest = orig / 5;
    const int u = rest & 1, b = rest >> 1;

    const u16* Ah = Wggh + (u ? 512 : 0);
    const u16* Al = Wggl + (u ? 512 : 0);
    const u16* Bh = u ? tnth : pnth;
    const u16* Bl = u ? tntl : pntl;

    __shared__ u16 lds[32768];
    f4 acc[4][4];
    const f4 z4 = {0.f, 0.f, 0.f, 0.f};
#pragma unroll
    for (int i = 0; i < 4; ++i)
#pragma unroll
        for (int j = 0; j < 4; ++j) acc[i][j] = z4;

    core2(Ah, Al, Bh, Bl, 1024, 512, 512, 0, b * 640 + ot * 128, lds, acc);

    u16* Uh = u ? U2h : U1h;
    u16* Ul = u ? U2l : U1l;
    const int l = threadIdx.x & 63, w = threadIdx.x >> 6;
    const int wr = w >> 1, wc = w & 1;
#pragma unroll
    for (int i = 0; i < 4; ++i)
#pragma unroll
        for (int j = 0; j < 4; ++j)
#pragma unroll
            for (int r = 0; r < 4; ++r) {
                const int irow = wr * 64 + i * 16 + ((l >> 4) << 2) + r;
                const int ocol = ot * 128 + wc * 64 + j * 16 + (l & 15);
                const float v = acc[i][j][r];
                const u16 hh = f2bf(v);
                const u16 lo = f2bf(v - bf2f(hh));
                const size_t off = ((size_t)b * 128 + irow) * 640 + ocol;
                Uh[off] = hh; Ul[off] = lo;
            }
}

// ---------------------------------------------------------------------------
// term partials: GGa[b][i][d] = sum_o U1[i][o]*theta_t[d][o]  (u=0)
//                GGb[b][i][d] = sum_o U2[i][o]*phi_t[d][o]    (u=1)
// 256 blocks = 8*32 swizzle.
// ---------------------------------------------------------------------------
__global__ __launch_bounds__(256) void gemm_term_p(
    const u16* __restrict__ U1h, const u16* __restrict__ U1l,
    const u16* __restrict__ U2h, const u16* __restrict__ U2l,
    const u16* __restrict__ tth, const u16* __restrict__ ttl,
    const u16* __restrict__ pth, const u16* __restrict__ ptl,
    float* __restrict__ GGa, float* __restrict__ GGb)
{
    const int h = blockIdx.x;
    const int orig = (h & 7) * 32 + (h >> 3);
    const int dt = orig & 3;
    const int u = (orig >> 2) & 1;
    const int b = orig >> 3;

    const u16* Ah = u ? U2h : U1h;
    const u16* Al = u ? U2l : U1l;
    const u16* Bh = u ? pth : tth;
    const u16* Bl = u ? ptl : ttl;
    float* G = u ? GGb : GGa;

    __shared__ u16 lds[32768];
    f4 acc[4][4];
    const f4 z4 = {0.f, 0.f, 0.f, 0.f};
#pragma unroll
    for (int i = 0; i < 4; ++i)
#pragma unroll
        for (int j = 0; j < 4; ++j) acc[i][j] = z4;

    core2(Ah, Al, Bh, Bl, 640, 640, 640,
          b * 128, b * 512 + dt * 128, lds, acc);

    const int l = threadIdx.x & 63, w = threadIdx.x >> 6;
    const int wr = w >> 1, wc = w & 1;
#pragma unroll
    for (int i = 0; i < 4; ++i)
#pragma unroll
        for (int j = 0; j < 4; ++j)
#pragma unroll
            for (int r = 0; r < 4; ++r) {
                const int irow = wr * 64 + i * 16 + ((l >> 4) << 2) + r;
                const int dcol = dt * 128 + wc * 64 + j * 16 + (l & 15);
                G[((size_t)b * 128 + irow) * 512 + dcol] = acc[i][j][r];
            }
}

// ---------------------------------------------------------------------------
// transpose: src [b*512+c][640] -> dst [b*640+o][512], 4 planes via z
// ---------------------------------------------------------------------------
__global__ __launch_bounds__(256) void transpose_y(
    const u16* __restrict__ s0, u16* __restrict__ d0,
    const u16* __restrict__ s1, u16* __restrict__ d1,
    const u16* __restrict__ s2, u16* __restrict__ d2,
    const u16* __restrict__ s3, u16* __restrict__ d3)
{
    const int pz = blockIdx.z;
    const int b = pz >> 2, pl = pz & 3;
    const u16* src = pl == 0 ? s0 : pl == 1 ? s1 : pl == 2 ? s2 : s3;
    u16* dst = pl == 0 ? d0 : pl == 1 ? d1 : pl == 2 ? d2 : d3;
    const int o0 = blockIdx.x * 64, c0 = blockIdx.y * 64;
    __shared__ u16 t[64][72];
    const int tid = threadIdx.x;
#pragma unroll
    for (int rdx = tid; rdx < 512; rdx += 256) {
        const int c = rdx >> 3, oc = (rdx & 7) << 3;
        *(bh8*)&t[c][oc] = *(const bh8*)&src[((size_t)b * 512 + c0 + c) * 640 + o0 + oc];
    }
    __syncthreads();
#pragma unroll
    for (int wdx = tid; wdx < 512; wdx += 256) {
        const int o = wdx >> 3, cc = (wdx & 7) << 3;
        u16 v[8];
#pragma unroll
        for (int e = 0; e < 8; ++e) v[e] = t[cc + e][o];
        *(bh8*)&dst[((size_t)b * 640 + o0 + o) * 512 + c0 + cc] = *(bh8*)&v[0];
    }
}

// ---------------------------------------------------------------------------
// fp32 -> bf16 hi/lo planes (X and W_gg)
// ---------------------------------------------------------------------------
__global__ __launch_bounds__(256) void conv_split(
    const float* __restrict__ in, u16* __restrict__ hi, u16* __restrict__ lo, long n8)
{
    long i = (long)blockIdx.x * 256 + threadIdx.x;
    const long stride = (long)gridDim.x * 256;
    for (; i < n8; i += stride) {
        const float4 a = ((const float4*)in)[2 * i];
        const float4 b = ((const float4*)in)[2 * i + 1];
        const float v[8] = {a.x, a.y, a.z, a.w, b.x, b.y, b.z, b.w};
        unsigned hw[4], lw[4];
#pragma unroll
        for (int k = 0; k < 4; ++k) {
            const u16 h0 = f2bf(v[2 * k]), h1 = f2bf(v[2 * k + 1]);
            const u16 l0 = f2bf(v[2 * k] - bf2f(h0)), l1 = f2bf(v[2 * k + 1] - bf2f(h1));
            hw[k] = (unsigned)h0 | ((unsigned)h1 << 16);
            lw[k] = (unsigned)l0 | ((unsigned)l1 << 16);
        }
        *(uint4*)&hi[8 * i] = make_uint4(hw[0], hw[1], hw[2], hw[3]);
        *(uint4*)&lo[8 * i] = make_uint4(lw[0], lw[1], lw[2], lw[3]);
    }
}

// 3 weights [rows][2304] -> padded [640][2304] hi/lo, zero rows >= rows
__global__ __launch_bounds__(256) void conv_w_pad3(
    const float* __restrict__ Wg, const float* __restrict__ Wt,
    const float* __restrict__ Wp,
    u16* __restrict__ Hg, u16* __restrict__ Lg,
    u16* __restrict__ Ht, u16* __restrict__ Lt,
    u16* __restrict__ Hp, u16* __restrict__ Lp,
    int rows, long n8)
{
    const int wsel = blockIdx.y;
    const float* W = wsel == 0 ? Wg : wsel == 1 ? Wt : Wp;
    u16* hi = wsel == 0 ? Hg : wsel == 1 ? Ht : Hp;
    u16* lo = wsel == 0 ? Lg : wsel == 1 ? Lt : Lp;

    const long i = (long)blockIdx.x * 256 + threadIdx.x;
    if (i >= n8) return;
    const long e = i * 8;
    const int row = (int)(e / 2304);
    unsigned hw[4] = {0, 0, 0, 0}, lw[4] = {0, 0, 0, 0};
    if (row < rows) {
        const float4 a = ((const float4*)W)[2 * i];
        const float4 b = ((const float4*)W)[2 * i + 1];
        const float v[8] = {a.x, a.y, a.z, a.w, b.x, b.y, b.z, b.w};
#pragma unroll
        for (int k = 0; k < 4; ++k) {
            const u16 h0 = f2bf(v[2 * k]), h1 = f2bf(v[2 * k + 1]);
            const u16 l0 = f2bf(v[2 * k] - bf2f(h0)), l1 = f2bf(v[2 * k + 1] - bf2f(h1));
            hw[k] = (unsigned)h0 | ((unsigned)h1 << 16);
            lw[k] = (unsigned)l0 | ((unsigned)l1 << 16);
        }
    }
    *(uint4*)&hi[8 * i] = make_uint4(hw[0], hw[1], hw[2], hw[3]);
    *(uint4*)&lo[8 * i] = make_uint4(lw[0], lw[1], lw[2], lw[3]);
}

// ---------------------------------------------------------------------------
// gate[b][d] = sigmoid(bn2(sum_o Wc2[o]*relu(bn1(sum_j Wc1[o][j]*yc[b][j][d]))))
// yc[0] = mean of y_gx (from gxc_part, 5 partials); yc[1+i] = relu(bn_gg(GGa+GGb))
// ---------------------------------------------------------------------------
__global__ __launch_bounds__(256)
void gate_kernel(const float* __restrict__ gxp,
                 const float* __restrict__ GGa, const float* __restrict__ GGb,
                 const float* __restrict__ bngg,
                 const float* __restrict__ Wc1, const float* __restrict__ bn1,
                 const float* __restrict__ Wc2, const float* __restrict__ bn2,
                 float* __restrict__ gate, int IC, int D, int OC)
{
    const int b  = blockIdx.y;
    const int d0 = blockIdx.x * 64;

    __shared__ float yc_s[129][64];
    __shared__ float part[4][64];

    const int tid = threadIdx.x;
    for (int idx = tid; idx < 129 * 64; idx += 256) {
        const int j = idx >> 6, d = idx & 63;
        float v;
        if (j == 0) {
            float s = 0.f;
#pragma unroll
            for (int t = 0; t < 5; ++t)
                s += gxp[(size_t)t * 16384 + (size_t)b * 512 + d0 + d];
            v = s * (1.f / 576.f);
        } else {
            const int i = j - 1;
            const float g = bngg[i], be = bngg[128 + i];
            const float m = bngg[256 + i], vv = bngg[384 + i];
            const float sc = g * rsqrtf(vv + EPSV);
            const float sh = be - m * sc;
            const size_t o = ((size_t)b * IC + i) * D + d0 + d;
            v = fmaxf((GGa[o] + GGb[o]) * sc + sh, 0.f);
        }
        yc_s[j][d] = v;
    }
    __syncthreads();

    const int d = tid & 63;
    const int q = tid >> 6;
    float acc2 = 0.f;
    for (int o = q * 16; o < q * 16 + 16; ++o) {
        float s = 0.f;
        const float* __restrict__ w = &Wc1[o * 129];
        for (int j = 0; j < 129; ++j) s = fmaf(w[j], yc_s[j][d], s);
        const float g1 = bn1[o], be1 = bn1[OC + o], m1 = bn1[2 * OC + o], v1 = bn1[3 * OC + o];
        const float sc = g1 / sqrtf(v1 + EPSV);
        const float w1 = fmaxf(s * sc + (be1 - m1 * sc), 0.f);
        acc2 = fmaf(Wc2[o], w1, acc2);
    }
    part[q][d] = acc2;
    __syncthreads();
    if (q == 0) {
        const float s = part[0][d] + part[1][d] + part[2][d] + part[3][d];
        const float g2 = bn2[0], be2 = bn2[1], m2 = bn2[2], v2 = bn2[3];
        const float sc = g2 / sqrtf(v2 + EPSV);
        const float wy = s * sc + (be2 - m2 * sc);
        gate[b * D + d0 + d] = 1.f / (1.f + expf(-wy));
    }
}

// ---------------------------------------------------------------------------
// out = x * (1 + gate[b][c])
// ---------------------------------------------------------------------------
__global__ __launch_bounds__(256)
void final_kernel(const float* __restrict__ x, const float* __restrict__ gate,
                  float* __restrict__ out, long n4, int sp4)
{
    long i = (long)blockIdx.x * blockDim.x + threadIdx.x;
    const long stride = (long)gridDim.x * blockDim.x;
    for (; i < n4; i += stride) {
        float4 v = ((const float4*)x)[i];
        const long bc = i / sp4;
        const float gm = 1.f + gate[bc];
        v.x *= gm; v.y *= gm; v.z *= gm; v.w *= gm;
        ((float4*)out)[i] = v;
    }
}

// ---------------------------------------------------------------------------
extern "C" void kernel_launch(void* const* d_in, const int* in_sizes, int n_in,
                              void* d_out, int out_size, void* d_ws, size_t ws_size,
                              hipStream_t stream)
{
    const float* x        = (const float*)d_in[0];
    const float* W_theta  = (const float*)d_in[1];
    const float* bn_theta = (const float*)d_in[2];
    const float* W_phi    = (const float*)d_in[3];
    const float* bn_phi   = (const float*)d_in[4];
    const float* W_gx     = (const float*)d_in[5];
    const float* bn_gx    = (const float*)d_in[6];
    const float* W_gg     = (const float*)d_in[7];
    const float* bn_gg    = (const float*)d_in[8];
    const float* W_c1     = (const float*)d_in[9];
    const float* bn_c1    = (const float*)d_in[10];
    const float* W_c2     = (const float*)d_in[11];
    const float* bn_c2    = (const float*)d_in[12];
    float* out = (float*)d_out;

    const int B = 32, C = 512, S = 2304, O = 576, OP = 640, IC = 128, OC = 64;
    const size_t P  = (size_t)B * C * OP;      // y-plane elems  (10,485,760)
    const size_t WP = (size_t)OP * S;          // W-plane elems  (1,474,560)
    const size_t UP = (size_t)B * IC * OP;     // U-plane elems  (2,621,440)

    // ---- d_out arena (dead before final_kernel) ----
    u16* tth = (u16*)d_out;          // theta_t hi  [B*512][640]
    u16* ttl = tth + P;
    u16* pth = ttl + P;              // phi_t hi
    u16* ptl = pth + P;
    u16* Wgh = ptl + P;              // stage-1 W planes (gx, theta, phi)
    u16* Wgl = Wgh + WP;
    u16* Wth = Wgl + WP;
    u16* Wtl = Wth + WP;
    u16* Wph = Wtl + WP;
    u16* Wpl = Wph + WP;
    u16* wggh = Wpl + WP;            // Wgg planes [128][1024]
    u16* wggl = wggh + (size_t)IC * 1024;
    u16* u1h = wggl + (size_t)IC * 1024;
    u16* u1l = u1h + UP;
    u16* u2h = u1l + UP;
    u16* u2l = u2h + UP;
    float* GGa = (float*)(u2l + UP); // [B][128][512] fp32 partials
    float* GGb = GGa + (size_t)B * IC * C;

    // ---- ws ----
    u16* Xhi  = (u16*)d_ws;                          // [B*512][2304]
    u16* Xlo  = Xhi + (size_t)B * C * S;
    // transposed planes overlay the (dead after stage-1) X region:
    u16* tnth = (u16*)d_ws;                          // theta_nt [B*640][512]
    u16* tntl = tnth + P;
    u16* pnth = tntl + P;
    u16* pntl = pnth + P;
    float* gxc_part = (float*)(Xlo + (size_t)B * C * S);  // [5][B*512]
    float* gate = gxc_part + (size_t)5 * B * C;           // [B][512]

    const dim3 blk(256);

    // 1) weight conversions (one merged launch for the 3 stage-1 weights)
    const long wN8 = (long)WP / 8;
    conv_w_pad3<<<dim3((unsigned)(wN8 / 256), 3), blk, 0, stream>>>(
        W_gx, W_theta, W_phi, Wgh, Wgl, Wth, Wtl, Wph, Wpl, O, wN8);
    conv_split<<<dim3(64), blk, 0, stream>>>(W_gg, wggh, wggl, (long)IC * 1024 / 8);

    // 2) split X; stage-1 (3 weights fused, 2-barrier counted-vmcnt pipeline)
    conv_split<<<dim3(2048), blk, 0, stream>>>(x, Xhi, Xlo, (long)B * C * S / 8);
    gemm_s1_v9<<<dim3(960), dim3(512), 0, stream>>>(
        Xhi, Xlo, Wgh, Wgl, Wth, Wtl, Wph, Wpl,
        bn_gx, bn_theta, bn_phi,
        gxc_part, tth, ttl, pth, ptl);

    // 3) transpose theta_t/phi_t hi+lo into ws (X region is dead now)
    transpose_y<<<dim3(10, 8, 128), blk, 0, stream>>>(
        tth, tnth, ttl, tntl, pth, pnth, ptl, pntl);

    // 4) U = Wgg * {phi_nt, theta_nt}
    gemm_u<<<dim3(320), blk, 0, stream>>>(wggh, wggl, tnth, tntl, pnth, pntl,
                                          u1h, u1l, u2h, u2l);

    // 5) GG partials on full chip (bn+relu folded into gate staging)
    gemm_term_p<<<dim3(256), blk, 0, stream>>>(u1h, u1l, u2h, u2l,
                                               tth, ttl, pth, ptl, GGa, GGb);

    // 6) gate (reads GGa+GGb with bn_gg inline; gx mean from 5 partials)
    gate_kernel<<<dim3(C / 64, B), blk, 0, stream>>>(
        gxc_part, GGa, GGb, bn_gg, W_c1, bn_c1, W_c2, bn_c2,
        gate, IC, C, OC);

    // 7) out = x * (1 + gate)
    final_kernel<<<dim3(2048), blk, 0, stream>>>(x, gate, out,
                                                 (long)B * C * S / 4, S / 4);
}

// Round 14
// 610.695 us; speedup vs baseline: 1.0706x; 1.0706x over previous
//
#include <hip/hip_runtime.h>
#include <cstdint>

#define EPSV 1e-5f
typedef unsigned short u16;
typedef __attribute__((ext_vector_type(8))) short bh8;   // 8 bf16 (4 VGPRs)
typedef __attribute__((ext_vector_type(4))) float f4;

__device__ __forceinline__ float bf2f(u16 h) { return __uint_as_float((unsigned)h << 16); }
__device__ __forceinline__ u16 f2bf(float x) {
    unsigned u = __float_as_uint(x);
    u += 0x7fffu + ((u >> 16) & 1u);          // RNE
    return (u16)(u >> 16);
}

// async global->LDS, 16B per lane; LDS dest = wave-uniform base + lane*16
__device__ __forceinline__ void gl16(const void* g, const void* s) {
    __builtin_amdgcn_global_load_lds(
        reinterpret_cast<const __attribute__((address_space(1))) void*>((uintptr_t)g),
        reinterpret_cast<__attribute__((address_space(3))) void*>((unsigned)(uintptr_t)s),
        16, 0, 0);
}

// ---------------------------------------------------------------------------
// 128x128 2-phase dbuf NT hi/lo core (4 waves, 64 KB LDS) — round-6 proven.
// Chunk-XOR swizzle both sides. Used by gemm_u / gemm_term_p.
// ---------------------------------------------------------------------------
__device__ __forceinline__ void core2(
    const u16* __restrict__ Ah, const u16* __restrict__ Al,
    const u16* __restrict__ Bh, const u16* __restrict__ Bl,
    long ldA, long ldB, int K, int rowA0, int rowB0,
    u16* lds, f4 acc[4][4])
{
    const int tid = threadIdx.x, l = tid & 63, w = tid >> 6;
    const int wr = w >> 1, wc = w & 1;
    const int srow = tid >> 2;
    const int schunk = ((tid & 3) ^ ((tid >> 3) & 3)) << 3;     // elems
    const size_t aoff = (size_t)(rowA0 + srow) * ldA + schunk;
    const size_t boff = (size_t)(rowB0 + srow) * ldB + schunk;
    const size_t a64 = (size_t)64 * ldA, b64 = (size_t)64 * ldB;
    const int rr = l & 15, cq = l >> 4;
    const int roff = rr * 64 + (((cq ^ ((rr >> 1) & 3))) << 4); // bytes
    char* const base0 = (char*)lds;
    char* const base1 = (char*)lds + 32768;
    const int nt = K >> 5;

#define STAGE_SWZ(base, s0) do { \
    gl16(Ah + aoff + (s0),       (base) +         w * 1024); \
    gl16(Ah + aoff + a64 + (s0), (base) +  4096 + w * 1024); \
    gl16(Al + aoff + (s0),       (base) +  8192 + w * 1024); \
    gl16(Al + aoff + a64 + (s0), (base) + 12288 + w * 1024); \
    gl16(Bh + boff + (s0),       (base) + 16384 + w * 1024); \
    gl16(Bh + boff + b64 + (s0), (base) + 20480 + w * 1024); \
    gl16(Bl + boff + (s0),       (base) + 24576 + w * 1024); \
    gl16(Bl + boff + b64 + (s0), (base) + 28672 + w * 1024); \
} while (0)

    STAGE_SWZ(base0, 0);
    __syncthreads();
    int p = 0;
    for (int t = 0; t < nt; ++t) {
        if (t + 1 < nt) STAGE_SWZ(p ? base0 : base1, (size_t)(t + 1) << 5);
        const char* buf = p ? base1 : base0;
        bh8 a_h[4], a_l[4], b_h[4], b_l[4];
#pragma unroll
        for (int i = 0; i < 4; ++i) {
            a_h[i] = *(const bh8*)(buf + (wr * 4 + i) * 1024 + roff);
            a_l[i] = *(const bh8*)(buf + 8192 + (wr * 4 + i) * 1024 + roff);
            b_h[i] = *(const bh8*)(buf + 16384 + (wc * 4 + i) * 1024 + roff);
            b_l[i] = *(const bh8*)(buf + 24576 + (wc * 4 + i) * 1024 + roff);
        }
#pragma unroll
        for (int i = 0; i < 4; ++i)
#pragma unroll
            for (int j = 0; j < 4; ++j)
                acc[i][j] = __builtin_amdgcn_mfma_f32_16x16x32_bf16(a_h[i], b_h[j], acc[i][j], 0, 0, 0);
#pragma unroll
        for (int i = 0; i < 4; ++i)
#pragma unroll
            for (int j = 0; j < 4; ++j)
                acc[i][j] = __builtin_amdgcn_mfma_f32_16x16x32_bf16(a_h[i], b_l[j], acc[i][j], 0, 0, 0);
#pragma unroll
        for (int i = 0; i < 4; ++i)
#pragma unroll
            for (int j = 0; j < 4; ++j)
                acc[i][j] = __builtin_amdgcn_mfma_f32_16x16x32_bf16(a_l[i], b_h[j], acc[i][j], 0, 0, 0);
        __syncthreads();
        p ^= 1;
    }
#undef STAGE_SWZ
}

// ---------------------------------------------------------------------------
// Stage-1 v6b: 3-phase counted-vmcnt ring (512 thr, 8 waves, BM=256 x BN=128,
// BK=32, 3x48KB LDS) with the gx (wi==0) row-mean FUSED: gx blocks reduce y
// over o in-register/LDS and write deterministic partials gxc_part[otw][B*512].
// ---------------------------------------------------------------------------
__global__ __launch_bounds__(512) void gemm_s1_v6b(
    const u16* __restrict__ Xh, const u16* __restrict__ Xl,
    const u16* __restrict__ W0h, const u16* __restrict__ W0l,
    const u16* __restrict__ W1h, const u16* __restrict__ W1l,
    const u16* __restrict__ W2h, const u16* __restrict__ W2l,
    const float* __restrict__ bn0, const float* __restrict__ bn1,
    const float* __restrict__ bn2,
    float* __restrict__ gxc_part,
    u16* __restrict__ Y1h, u16* __restrict__ Y1l,
    u16* __restrict__ Y2h, u16* __restrict__ Y2l)
{
    const int h = blockIdx.x;
    const int orig = (h & 7) * 120 + (h >> 3);
    const int ow = orig % 15;
    const int rest = orig / 15;               // 0..63
    const int ct = rest & 1, bz = rest >> 1;
    const int wi = ow / 5, otw = ow % 5;
    const bool full = (wi != 0);

    const u16* Bh = wi == 0 ? W0h : wi == 1 ? W1h : W2h;
    const u16* Bl = wi == 0 ? W0l : wi == 1 ? W1l : W2l;
    const float* bnp = wi == 0 ? bn0 : wi == 1 ? bn1 : bn2;
    u16* Yh = wi == 1 ? Y1h : Y2h;
    u16* Yl = wi == 1 ? Y1l : Y2l;

    __shared__ u16 lds[73728];                // 144 KB = 3 x 48 KB ring

    const int tid = threadIdx.x, l = tid & 63, w = tid >> 6;
    const int wm = w >> 1, wn = w & 1;        // 4(M) x 2(N) wave grid
    const long ldK = 2304;
    const int rowA0 = bz * 512 + ct * 256;
    const int rowB0 = otw * 128;
    const int srow = tid >> 2;                // 0..127
    const int schunk = ((tid & 3) ^ ((tid >> 3) & 3)) << 3;
    const size_t aoff = (size_t)(rowA0 + srow) * ldK + schunk;
    const size_t boff = (size_t)(rowB0 + srow) * ldK + schunk;
    const size_t a128 = (size_t)128 * ldK;
    const int rr = l & 15, cq2 = l >> 4;
    const int roff = rr * 64 + ((cq2 ^ ((rr >> 1) & 3)) << 4);
    char* const ldsb = (char*)lds;
    const int nt = 72;                        // 2304/32

#define ST_AHI(sb, s0) do { \
    gl16(Xh + aoff + (s0),        (sb) +         w * 1024); \
    gl16(Xh + aoff + a128 + (s0), (sb) +  8192 + w * 1024); } while (0)
#define ST_ALO(sb, s0) do { \
    gl16(Xl + aoff + (s0),        (sb) + 16384 + w * 1024); \
    gl16(Xl + aoff + a128 + (s0), (sb) + 24576 + w * 1024); } while (0)
#define ST_BHI(sb, s0) gl16(Bh + boff + (s0), (sb) + 32768 + w * 1024)
#define ST_BLO(sb, s0) gl16(Bl + boff + (s0), (sb) + 40960 + w * 1024)

    f4 acc[4][4];
    const f4 z4 = {0.f, 0.f, 0.f, 0.f};
#pragma unroll
    for (int i = 0; i < 4; ++i)
#pragma unroll
        for (int j = 0; j < 4; ++j) acc[i][j] = z4;

    // prologue: stage tiles 0 (buf0) and 1 (buf1); counted wait on tile 0
    ST_AHI(ldsb, 0); if (full) ST_ALO(ldsb, 0); ST_BHI(ldsb, 0); ST_BLO(ldsb, 0);
    ST_AHI(ldsb + 49152, 32); if (full) ST_ALO(ldsb + 49152, 32);
    ST_BHI(ldsb + 49152, 32); ST_BLO(ldsb + 49152, 32);
    if (full) asm volatile("s_waitcnt vmcnt(6)" ::: "memory");
    else      asm volatile("s_waitcnt vmcnt(4)" ::: "memory");
    __builtin_amdgcn_sched_barrier(0);
    __builtin_amdgcn_s_barrier();

    for (int t = 0; t < nt; ++t) {
        const char* buf = ldsb + (t % 3) * 49152;
        char* sbuf = ldsb + ((t + 2) % 3) * 49152;
        const bool pre = (t + 2 < nt);
        const int s0 = (t + 2) << 5;

        bh8 a_h[4], b_h[4], a_l[4], b_l[4];
        // ---- Phase A: hh ----
#pragma unroll
        for (int i = 0; i < 4; ++i)
            a_h[i] = *(const bh8*)(buf + (wm * 4 + i) * 1024 + roff);
#pragma unroll
        for (int j = 0; j < 4; ++j)
            b_h[j] = *(const bh8*)(buf + 32768 + (wn * 4 + j) * 1024 + roff);
        if (pre) ST_AHI(sbuf, s0);
        __builtin_amdgcn_s_barrier();
        __builtin_amdgcn_s_setprio(1);
#pragma unroll
        for (int i = 0; i < 4; ++i)
#pragma unroll
            for (int j = 0; j < 4; ++j)
                acc[i][j] = __builtin_amdgcn_mfma_f32_16x16x32_bf16(a_h[i], b_h[j], acc[i][j], 0, 0, 0);
        __builtin_amdgcn_s_setprio(0);
        __builtin_amdgcn_s_barrier();
        // ---- Phase B: hl ----
        if (full) {
#pragma unroll
            for (int i = 0; i < 4; ++i)
                a_l[i] = *(const bh8*)(buf + 16384 + (wm * 4 + i) * 1024 + roff);
        }
#pragma unroll
        for (int j = 0; j < 4; ++j)
            b_l[j] = *(const bh8*)(buf + 40960 + (wn * 4 + j) * 1024 + roff);
        if (pre) { if (full) ST_ALO(sbuf, s0); ST_BHI(sbuf, s0); }
        __builtin_amdgcn_s_barrier();
        __builtin_amdgcn_s_setprio(1);
#pragma unroll
        for (int i = 0; i < 4; ++i)
#pragma unroll
            for (int j = 0; j < 4; ++j)
                acc[i][j] = __builtin_amdgcn_mfma_f32_16x16x32_bf16(a_h[i], b_l[j], acc[i][j], 0, 0, 0);
        __builtin_amdgcn_s_setprio(0);
        __builtin_amdgcn_s_barrier();
        // ---- Phase C: lh + counted wait for tile t+1 ----
        if (pre) ST_BLO(sbuf, s0);
        if (t + 1 < nt) {
            if (pre) {
                if (full) asm volatile("s_waitcnt vmcnt(6)" ::: "memory");
                else      asm volatile("s_waitcnt vmcnt(4)" ::: "memory");
            } else {
                asm volatile("s_waitcnt vmcnt(0)" ::: "memory");
            }
            __builtin_amdgcn_sched_barrier(0);
        }
        __builtin_amdgcn_s_barrier();
        if (full) {
            __builtin_amdgcn_s_setprio(1);
#pragma unroll
            for (int i = 0; i < 4; ++i)
#pragma unroll
                for (int j = 0; j < 4; ++j)
                    acc[i][j] = __builtin_amdgcn_mfma_f32_16x16x32_bf16(a_l[i], b_h[j], acc[i][j], 0, 0, 0);
            __builtin_amdgcn_s_setprio(0);
        }
        __builtin_amdgcn_s_barrier();
    }
#undef ST_AHI
#undef ST_ALO
#undef ST_BHI
#undef ST_BLO

    const int mb = ct * 256 + wm * 64;        // c within batch
    const int nbw = otw * 128 + wn * 64;      // o
    const int lm = l & 15, cq = l >> 4;

    if (wi == 0) {
        // fused row-mean partial: sum y over this block's o-range per c row
        float rs[4][4] = {};
#pragma unroll
        for (int j = 0; j < 4; ++j) {
            const int o = nbw + j * 16 + lm;
            const bool val = (o < 576);
            float sc = 0.f, sh = 0.f;
            if (val) {
                const float gg = bnp[o], be = bnp[576 + o], mm = bnp[1152 + o], vv = bnp[1728 + o];
                sc = gg * rsqrtf(vv + EPSV);
                sh = be - mm * sc;
            }
#pragma unroll
            for (int i = 0; i < 4; ++i)
#pragma unroll
                for (int r = 0; r < 4; ++r)
                    rs[i][r] += val ? fmaxf(acc[i][j][r] * sc + sh, 0.f) : 0.f;
        }
        __syncthreads();                      // safe reuse of lds
        float* ldsF = (float*)lds;
#pragma unroll
        for (int i = 0; i < 4; ++i)
#pragma unroll
            for (int r = 0; r < 4; ++r) {
                float v = rs[i][r];
                v += __shfl_xor(v, 1, 64);
                v += __shfl_xor(v, 2, 64);
                v += __shfl_xor(v, 4, 64);
                v += __shfl_xor(v, 8, 64);
                if (lm == 0)
                    ldsF[wn * 256 + wm * 64 + i * 16 + cq * 4 + r] = v;
            }
        __syncthreads();
        if (tid < 256)
            gxc_part[(size_t)otw * 16384 + (size_t)bz * 512 + ct * 256 + tid]
                = ldsF[tid] + ldsF[256 + tid];
    } else {
        // epilogue: bn + relu, hi/lo split, write Y^T [b*512+c][640]
#pragma unroll
        for (int j = 0; j < 4; ++j) {
            const int o = nbw + j * 16 + lm;
            const bool val = (o < 576);
            float sc = 0.f, sh = 0.f;
            if (val) {
                const float gg = bnp[o], be = bnp[576 + o], mm = bnp[1152 + o], vv = bnp[1728 + o];
                sc = gg * rsqrtf(vv + EPSV);
                sh = be - mm * sc;
            }
#pragma unroll
            for (int i = 0; i < 4; ++i) {
                const int c = mb + i * 16 + (cq << 2);
#pragma unroll
                for (int r = 0; r < 4; ++r) {
                    const float y = val ? fmaxf(acc[i][j][r] * sc + sh, 0.f) : 0.f;
                    const u16 hh = f2bf(y);
                    const u16 lo = f2bf(y - bf2f(hh));
                    const size_t off = ((size_t)bz * 512 + c + r) * 640 + o;
                    Yh[off] = hh; Yl[off] = lo;
                }
            }
        }
    }
}

// ---------------------------------------------------------------------------
// U GEMMs: U1[i][o] = sum_j Wgg[i][j]    * phi_nt[o][j]
//          U2[i][o] = sum_j Wgg[i][512+j]* theta_nt[o][j]
// written as hi/lo planes [32][128][640]. 320 blocks = 8*40 swizzle.
// ---------------------------------------------------------------------------
__global__ __launch_bounds__(256) void gemm_u(
    const u16* __restrict__ Wggh, const u16* __restrict__ Wggl,
    const u16* __restrict__ tnth, const u16* __restrict__ tntl,
    const u16* __restrict__ pnth, const u16* __restrict__ pntl,
    u16* __restrict__ U1h, u16* __restrict__ U1l,
    u16* __restrict__ U2h, u16* __restrict__ U2l)
{
    const int h = blockIdx.x;
    const int orig = (h & 7) * 40 + (h >> 3);
    const int ot = orig % 5;
    const int rest = orig / 5;
    const int u = rest & 1, b = rest >> 1;

    const u16* Ah = Wggh + (u ? 512 : 0);
    const u16* Al = Wggl + (u ? 512 : 0);
    const u16* Bh = u ? tnth : pnth;
    const u16* Bl = u ? tntl : pntl;

    __shared__ u16 lds[32768];
    f4 acc[4][4];
    const f4 z4 = {0.f, 0.f, 0.f, 0.f};
#pragma unroll
    for (int i = 0; i < 4; ++i)
#pragma unroll
        for (int j = 0; j < 4; ++j) acc[i][j] = z4;

    core2(Ah, Al, Bh, Bl, 1024, 512, 512, 0, b * 640 + ot * 128, lds, acc);

    u16* Uh = u ? U2h : U1h;
    u16* Ul = u ? U2l : U1l;
    const int l = threadIdx.x & 63, w = threadIdx.x >> 6;
    const int wr = w >> 1, wc = w & 1;
#pragma unroll
    for (int i = 0; i < 4; ++i)
#pragma unroll
        for (int j = 0; j < 4; ++j)
#pragma unroll
            for (int r = 0; r < 4; ++r) {
                const int irow = wr * 64 + i * 16 + ((l >> 4) << 2) + r;
                const int ocol = ot * 128 + wc * 64 + j * 16 + (l & 15);
                const float v = acc[i][j][r];
                const u16 hh = f2bf(v);
                const u16 lo = f2bf(v - bf2f(hh));
                const size_t off = ((size_t)b * 128 + irow) * 640 + ocol;
                Uh[off] = hh; Ul[off] = lo;
            }
}

// ---------------------------------------------------------------------------
// term partials: GGa[b][i][d] = sum_o U1[i][o]*theta_t[d][o]  (u=0)
//                GGb[b][i][d] = sum_o U2[i][o]*phi_t[d][o]    (u=1)
// 256 blocks = 8*32 swizzle.
// ---------------------------------------------------------------------------
__global__ __launch_bounds__(256) void gemm_term_p(
    const u16* __restrict__ U1h, const u16* __restrict__ U1l,
    const u16* __restrict__ U2h, const u16* __restrict__ U2l,
    const u16* __restrict__ tth, const u16* __restrict__ ttl,
    const u16* __restrict__ pth, const u16* __restrict__ ptl,
    float* __restrict__ GGa, float* __restrict__ GGb)
{
    const int h = blockIdx.x;
    const int orig = (h & 7) * 32 + (h >> 3);
    const int dt = orig & 3;
    const int u = (orig >> 2) & 1;
    const int b = orig >> 3;

    const u16* Ah = u ? U2h : U1h;
    const u16* Al = u ? U2l : U1l;
    const u16* Bh = u ? pth : tth;
    const u16* Bl = u ? ptl : ttl;
    float* G = u ? GGb : GGa;

    __shared__ u16 lds[32768];
    f4 acc[4][4];
    const f4 z4 = {0.f, 0.f, 0.f, 0.f};
#pragma unroll
    for (int i = 0; i < 4; ++i)
#pragma unroll
        for (int j = 0; j < 4; ++j) acc[i][j] = z4;

    core2(Ah, Al, Bh, Bl, 640, 640, 640,
          b * 128, b * 512 + dt * 128, lds, acc);

    const int l = threadIdx.x & 63, w = threadIdx.x >> 6;
    const int wr = w >> 1, wc = w & 1;
#pragma unroll
    for (int i = 0; i < 4; ++i)
#pragma unroll
        for (int j = 0; j < 4; ++j)
#pragma unroll
            for (int r = 0; r < 4; ++r) {
                const int irow = wr * 64 + i * 16 + ((l >> 4) << 2) + r;
                const int dcol = dt * 128 + wc * 64 + j * 16 + (l & 15);
                G[((size_t)b * 128 + irow) * 512 + dcol] = acc[i][j][r];
            }
}

// ---------------------------------------------------------------------------
// transpose: src [b*512+c][640] -> dst [b*640+o][512], 4 planes via z
// ---------------------------------------------------------------------------
__global__ __launch_bounds__(256) void transpose_y(
    const u16* __restrict__ s0, u16* __restrict__ d0,
    const u16* __restrict__ s1, u16* __restrict__ d1,
    const u16* __restrict__ s2, u16* __restrict__ d2,
    const u16* __restrict__ s3, u16* __restrict__ d3)
{
    const int pz = blockIdx.z;
    const int b = pz >> 2, pl = pz & 3;
    const u16* src = pl == 0 ? s0 : pl == 1 ? s1 : pl == 2 ? s2 : s3;
    u16* dst = pl == 0 ? d0 : pl == 1 ? d1 : pl == 2 ? d2 : d3;
    const int o0 = blockIdx.x * 64, c0 = blockIdx.y * 64;
    __shared__ u16 t[64][72];
    const int tid = threadIdx.x;
#pragma unroll
    for (int rdx = tid; rdx < 512; rdx += 256) {
        const int c = rdx >> 3, oc = (rdx & 7) << 3;
        *(bh8*)&t[c][oc] = *(const bh8*)&src[((size_t)b * 512 + c0 + c) * 640 + o0 + oc];
    }
    __syncthreads();
#pragma unroll
    for (int wdx = tid; wdx < 512; wdx += 256) {
        const int o = wdx >> 3, cc = (wdx & 7) << 3;
        u16 v[8];
#pragma unroll
        for (int e = 0; e < 8; ++e) v[e] = t[cc + e][o];
        *(bh8*)&dst[((size_t)b * 640 + o0 + o) * 512 + c0 + cc] = *(bh8*)&v[0];
    }
}

// ---------------------------------------------------------------------------
// fp32 -> bf16 hi/lo planes (X and W_gg)
// ---------------------------------------------------------------------------
__global__ __launch_bounds__(256) void conv_split(
    const float* __restrict__ in, u16* __restrict__ hi, u16* __restrict__ lo, long n8)
{
    long i = (long)blockIdx.x * 256 + threadIdx.x;
    const long stride = (long)gridDim.x * 256;
    for (; i < n8; i += stride) {
        const float4 a = ((const float4*)in)[2 * i];
        const float4 b = ((const float4*)in)[2 * i + 1];
        const float v[8] = {a.x, a.y, a.z, a.w, b.x, b.y, b.z, b.w};
        unsigned hw[4], lw[4];
#pragma unroll
        for (int k = 0; k < 4; ++k) {
            const u16 h0 = f2bf(v[2 * k]), h1 = f2bf(v[2 * k + 1]);
            const u16 l0 = f2bf(v[2 * k] - bf2f(h0)), l1 = f2bf(v[2 * k + 1] - bf2f(h1));
            hw[k] = (unsigned)h0 | ((unsigned)h1 << 16);
            lw[k] = (unsigned)l0 | ((unsigned)l1 << 16);
        }
        *(uint4*)&hi[8 * i] = make_uint4(hw[0], hw[1], hw[2], hw[3]);
        *(uint4*)&lo[8 * i] = make_uint4(lw[0], lw[1], lw[2], lw[3]);
    }
}

// 3 weights [rows][2304] -> padded [640][2304] hi/lo, zero rows >= rows
__global__ __launch_bounds__(256) void conv_w_pad3(
    const float* __restrict__ Wg, const float* __restrict__ Wt,
    const float* __restrict__ Wp,
    u16* __restrict__ Hg, u16* __restrict__ Lg,
    u16* __restrict__ Ht, u16* __restrict__ Lt,
    u16* __restrict__ Hp, u16* __restrict__ Lp,
    int rows, long n8)
{
    const int wsel = blockIdx.y;
    const float* W = wsel == 0 ? Wg : wsel == 1 ? Wt : Wp;
    u16* hi = wsel == 0 ? Hg : wsel == 1 ? Ht : Hp;
    u16* lo = wsel == 0 ? Lg : wsel == 1 ? Lt : Lp;

    const long i = (long)blockIdx.x * 256 + threadIdx.x;
    if (i >= n8) return;
    const long e = i * 8;
    const int row = (int)(e / 2304);
    unsigned hw[4] = {0, 0, 0, 0}, lw[4] = {0, 0, 0, 0};
    if (row < rows) {
        const float4 a = ((const float4*)W)[2 * i];
        const float4 b = ((const float4*)W)[2 * i + 1];
        const float v[8] = {a.x, a.y, a.z, a.w, b.x, b.y, b.z, b.w};
#pragma unroll
        for (int k = 0; k < 4; ++k) {
            const u16 h0 = f2bf(v[2 * k]), h1 = f2bf(v[2 * k + 1]);
            const u16 l0 = f2bf(v[2 * k] - bf2f(h0)), l1 = f2bf(v[2 * k + 1] - bf2f(h1));
            hw[k] = (unsigned)h0 | ((unsigned)h1 << 16);
            lw[k] = (unsigned)l0 | ((unsigned)l1 << 16);
        }
    }
    *(uint4*)&hi[8 * i] = make_uint4(hw[0], hw[1], hw[2], hw[3]);
    *(uint4*)&lo[8 * i] = make_uint4(lw[0], lw[1], lw[2], lw[3]);
}

// ---------------------------------------------------------------------------
// gate[b][d] = sigmoid(bn2(sum_o Wc2[o]*relu(bn1(sum_j Wc1[o][j]*yc[b][j][d]))))
// yc[0] = mean of y_gx (from gxc_part, 5 partials); yc[1+i] = relu(bn_gg(GGa+GGb))
// ---------------------------------------------------------------------------
__global__ __launch_bounds__(256)
void gate_kernel(const float* __restrict__ gxp,
                 const float* __restrict__ GGa, const float* __restrict__ GGb,
                 const float* __restrict__ bngg,
                 const float* __restrict__ Wc1, const float* __restrict__ bn1,
                 const float* __restrict__ Wc2, const float* __restrict__ bn2,
                 float* __restrict__ gate, int IC, int D, int OC)
{
    const int b  = blockIdx.y;
    const int d0 = blockIdx.x * 64;

    __shared__ float yc_s[129][64];
    __shared__ float part[4][64];

    const int tid = threadIdx.x;
    for (int idx = tid; idx < 129 * 64; idx += 256) {
        const int j = idx >> 6, d = idx & 63;
        float v;
        if (j == 0) {
            float s = 0.f;
#pragma unroll
            for (int t = 0; t < 5; ++t)
                s += gxp[(size_t)t * 16384 + (size_t)b * 512 + d0 + d];
            v = s * (1.f / 576.f);
        } else {
            const int i = j - 1;
            const float g = bngg[i], be = bngg[128 + i];
            const float m = bngg[256 + i], vv = bngg[384 + i];
            const float sc = g * rsqrtf(vv + EPSV);
            const float sh = be - m * sc;
            const size_t o = ((size_t)b * IC + i) * D + d0 + d;
            v = fmaxf((GGa[o] + GGb[o]) * sc + sh, 0.f);
        }
        yc_s[j][d] = v;
    }
    __syncthreads();

    const int d = tid & 63;
    const int q = tid >> 6;
    float acc2 = 0.f;
    for (int o = q * 16; o < q * 16 + 16; ++o) {
        float s = 0.f;
        const float* __restrict__ w = &Wc1[o * 129];
        for (int j = 0; j < 129; ++j) s = fmaf(w[j], yc_s[j][d], s);
        const float g1 = bn1[o], be1 = bn1[OC + o], m1 = bn1[2 * OC + o], v1 = bn1[3 * OC + o];
        const float sc = g1 / sqrtf(v1 + EPSV);
        const float w1 = fmaxf(s * sc + (be1 - m1 * sc), 0.f);
        acc2 = fmaf(Wc2[o], w1, acc2);
    }
    part[q][d] = acc2;
    __syncthreads();
    if (q == 0) {
        const float s = part[0][d] + part[1][d] + part[2][d] + part[3][d];
        const float g2 = bn2[0], be2 = bn2[1], m2 = bn2[2], v2 = bn2[3];
        const float sc = g2 / sqrtf(v2 + EPSV);
        const float wy = s * sc + (be2 - m2 * sc);
        gate[b * D + d0 + d] = 1.f / (1.f + expf(-wy));
    }
}

// ---------------------------------------------------------------------------
// out = x * (1 + gate[b][c])
// ---------------------------------------------------------------------------
__global__ __launch_bounds__(256)
void final_kernel(const float* __restrict__ x, const float* __restrict__ gate,
                  float* __restrict__ out, long n4, int sp4)
{
    long i = (long)blockIdx.x * blockDim.x + threadIdx.x;
    const long stride = (long)gridDim.x * blockDim.x;
    for (; i < n4; i += stride) {
        float4 v = ((const float4*)x)[i];
        const long bc = i / sp4;
        const float gm = 1.f + gate[bc];
        v.x *= gm; v.y *= gm; v.z *= gm; v.w *= gm;
        ((float4*)out)[i] = v;
    }
}

// ---------------------------------------------------------------------------
extern "C" void kernel_launch(void* const* d_in, const int* in_sizes, int n_in,
                              void* d_out, int out_size, void* d_ws, size_t ws_size,
                              hipStream_t stream)
{
    const float* x        = (const float*)d_in[0];
    const float* W_theta  = (const float*)d_in[1];
    const float* bn_theta = (const float*)d_in[2];
    const float* W_phi    = (const float*)d_in[3];
    const float* bn_phi   = (const float*)d_in[4];
    const float* W_gx     = (const float*)d_in[5];
    const float* bn_gx    = (const float*)d_in[6];
    const float* W_gg     = (const float*)d_in[7];
    const float* bn_gg    = (const float*)d_in[8];
    const float* W_c1     = (const float*)d_in[9];
    const float* bn_c1    = (const float*)d_in[10];
    const float* W_c2     = (const float*)d_in[11];
    const float* bn_c2    = (const float*)d_in[12];
    float* out = (float*)d_out;

    const int B = 32, C = 512, S = 2304, O = 576, OP = 640, IC = 128, OC = 64;
    const size_t P  = (size_t)B * C * OP;      // y-plane elems  (10,485,760)
    const size_t WP = (size_t)OP * S;          // W-plane elems  (1,474,560)
    const size_t UP = (size_t)B * IC * OP;     // U-plane elems  (2,621,440)

    // ---- d_out arena (dead before final_kernel) ----
    u16* tth = (u16*)d_out;          // theta_t hi  [B*512][640]
    u16* ttl = tth + P;
    u16* pth = ttl + P;              // phi_t hi
    u16* ptl = pth + P;
    u16* Wgh = ptl + P;              // stage-1 W planes (gx, theta, phi)
    u16* Wgl = Wgh + WP;
    u16* Wth = Wgl + WP;
    u16* Wtl = Wth + WP;
    u16* Wph = Wtl + WP;
    u16* Wpl = Wph + WP;
    u16* wggh = Wpl + WP;            // Wgg planes [128][1024]
    u16* wggl = wggh + (size_t)IC * 1024;
    u16* u1h = wggl + (size_t)IC * 1024;
    u16* u1l = u1h + UP;
    u16* u2h = u1l + UP;
    u16* u2l = u2h + UP;
    float* GGa = (float*)(u2l + UP); // [B][128][512] fp32 partials
    float* GGb = GGa + (size_t)B * IC * C;

    // ---- ws ----
    u16* Xhi  = (u16*)d_ws;                          // [B*512][2304]
    u16* Xlo  = Xhi + (size_t)B * C * S;
    // transposed planes overlay the (dead after stage-1) X region:
    u16* tnth = (u16*)d_ws;                          // theta_nt [B*640][512]
    u16* tntl = tnth + P;
    u16* pnth = tntl + P;
    u16* pntl = pnth + P;
    float* gxc_part = (float*)(Xlo + (size_t)B * C * S);  // [5][B*512]
    float* gate = gxc_part + (size_t)5 * B * C;           // [B][512]

    const dim3 blk(256);

    // 1) weight conversions (one merged launch for the 3 stage-1 weights)
    const long wN8 = (long)WP / 8;
    conv_w_pad3<<<dim3((unsigned)(wN8 / 256), 3), blk, 0, stream>>>(
        W_gx, W_theta, W_phi, Wgh, Wgl, Wth, Wtl, Wph, Wpl, O, wN8);
    conv_split<<<dim3(64), blk, 0, stream>>>(W_gg, wggh, wggl, (long)IC * 1024 / 8);

    // 2) split X; stage-1 (3 weights fused, counted-vmcnt pipeline, fused gx mean)
    conv_split<<<dim3(2048), blk, 0, stream>>>(x, Xhi, Xlo, (long)B * C * S / 8);
    gemm_s1_v6b<<<dim3(960), dim3(512), 0, stream>>>(
        Xhi, Xlo, Wgh, Wgl, Wth, Wtl, Wph, Wpl,
        bn_gx, bn_theta, bn_phi,
        gxc_part, tth, ttl, pth, ptl);

    // 3) transpose theta_t/phi_t hi+lo into ws (X region is dead now)
    transpose_y<<<dim3(10, 8, 128), blk, 0, stream>>>(
        tth, tnth, ttl, tntl, pth, pnth, ptl, pntl);

    // 4) U = Wgg * {phi_nt, theta_nt}
    gemm_u<<<dim3(320), blk, 0, stream>>>(wggh, wggl, tnth, tntl, pnth, pntl,
                                          u1h, u1l, u2h, u2l);

    // 5) GG partials on full chip (bn+relu folded into gate staging)
    gemm_term_p<<<dim3(256), blk, 0, stream>>>(u1h, u1l, u2h, u2l,
                                               tth, ttl, pth, ptl, GGa, GGb);

    // 6) gate (reads GGa+GGb with bn_gg inline; gx mean from 5 partials)
    gate_kernel<<<dim3(C / 64, B), blk, 0, stream>>>(
        gxc_part, GGa, GGb, bn_gg, W_c1, bn_c1, W_c2, bn_c2,
        gate, IC, C, OC);

    // 7) out = x * (1 + gate)
    final_kernel<<<dim3(2048), blk, 0, stream>>>(x, gate, out,
                                                 (long)B * C * S / 4, S / 4);
}